// Round 1
// baseline (2632.180 us; speedup 1.0000x reference)
//
#include <hip/hip_runtime.h>
#include <math.h>

#define N_ENT   100000
#define DIM     200
#define HD      100       // DIM/2
#define N_RELC  200
#define TM      32        // rows per block in fused matmul

__device__ __forceinline__ float invsqrt_pos(float x) {
    return x > 0.f ? (1.f / sqrtf(x)) : 0.f;
}

__global__ __launch_bounds__(256) void deg_kernel(
        const int* __restrict__ src, const int* __restrict__ dst,
        int* __restrict__ deg_in, int* __restrict__ deg_out, int n) {
    int i = blockIdx.x * blockDim.x + threadIdx.x;
    int stride = gridDim.x * blockDim.x;
    for (; i < n; i += stride) {
        atomicAdd(&deg_in[dst[i]], 1);
        atomicAdd(&deg_out[src[i]], 1);
    }
}

// One wave (64 lanes) per edge; does both directions.
__global__ __launch_bounds__(256) void scatter_kernel(
        const float* __restrict__ ent, const float* __restrict__ rel,
        const int* __restrict__ src, const int* __restrict__ dst,
        const int* __restrict__ etype,
        const int* __restrict__ deg_in, const int* __restrict__ deg_out,
        float* acc_in, float* acc_out, int n) {
    int gid   = blockIdx.x * blockDim.x + threadIdx.x;
    int wave  = gid >> 6;
    int lane  = threadIdx.x & 63;
    int nwav  = (gridDim.x * blockDim.x) >> 6;
    for (int e = wave; e < n; e += nwav) {
        int s = src[e], d = dst[e], t = etype[e];
        float norm_in  = invsqrt_pos((float)deg_in[d])  * invsqrt_pos((float)deg_in[s]);
        float norm_out = invsqrt_pos((float)deg_out[s]) * invsqrt_pos((float)deg_out[d]);

        // in direction: rotate(ent[s], rel[t]) scattered to acc_in[d]
        {
            const float* h = ent + (size_t)s * DIM;
            const float* r = rel + (size_t)t * DIM;
            float*       o = acc_in + (size_t)d * DIM;
            for (int p = lane; p < HD; p += 64) {
                float hre = h[p], him = h[p + HD];
                float rre = r[p], rim = r[p + HD];
                atomicAdd(&o[p],      (hre * rre - him * rim) * norm_in);
                atomicAdd(&o[p + HD], (hre * rim + him * rre) * norm_in);
            }
        }
        // out direction: rotate(ent[d], rel[t+N_REL]) scattered to acc_out[s]
        {
            const float* h = ent + (size_t)d * DIM;
            const float* r = rel + (size_t)(t + N_RELC) * DIM;
            float*       o = acc_out + (size_t)s * DIM;
            for (int p = lane; p < HD; p += 64) {
                float hre = h[p], him = h[p + HD];
                float rre = r[p], rim = r[p + HD];
                atomicAdd(&o[p],      (hre * rre - him * rim) * norm_out);
                atomicAdd(&o[p + HD], (hre * rim + him * rre) * norm_out);
            }
        }
    }
}

// Fused: pre = (acc_in@w_in + acc_out@w_out + rotate(ent,loop)@w_loop)/3 + bias
// acc_out lives in d_out; we read rows into LDS, then overwrite the same rows.
__global__ __launch_bounds__(256) void matmul_kernel(
        const float* __restrict__ acc_in, const float* acc_out,
        const float* __restrict__ ent, const float* __restrict__ loop_rel,
        const float* __restrict__ w_in, const float* __restrict__ w_out,
        const float* __restrict__ w_loop, const float* __restrict__ bias,
        float* out) {
    __shared__ float sIn[TM][DIM];
    __shared__ float sOut[TM][DIM];
    __shared__ float sLoop[TM][DIM];
    const int row0 = blockIdx.x * TM;
    const int tid  = threadIdx.x;

    // stage: each work item handles one (row, pair)
    for (int idx = tid; idx < TM * HD; idx += blockDim.x) {
        int r = idx / HD, p = idx % HD;
        int row = row0 + r;
        if (row < N_ENT) {
            size_t base = (size_t)row * DIM;
            sIn[r][p]       = acc_in[base + p];
            sIn[r][p + HD]  = acc_in[base + p + HD];
            sOut[r][p]      = acc_out[base + p];
            sOut[r][p + HD] = acc_out[base + p + HD];
            float e0 = ent[base + p], e1 = ent[base + p + HD];
            float l0 = loop_rel[p],   l1 = loop_rel[p + HD];
            sLoop[r][p]      = e0 * l0 - e1 * l1;
            sLoop[r][p + HD] = e0 * l1 + e1 * l0;
        }
    }
    __syncthreads();

    const int c = tid;           // thread owns one output column
    if (c >= DIM) return;
    float acc[TM];
#pragma unroll
    for (int r = 0; r < TM; ++r) acc[r] = 0.f;

    for (int k = 0; k < DIM; k += 4) {
        float wi[4], wo[4], wl[4];
#pragma unroll
        for (int u = 0; u < 4; ++u) {
            wi[u] = w_in [(k + u) * DIM + c];
            wo[u] = w_out[(k + u) * DIM + c];
            wl[u] = w_loop[(k + u) * DIM + c];
        }
#pragma unroll
        for (int r = 0; r < TM; ++r) {
            float4 ai = *(const float4*)&sIn[r][k];
            float4 ao = *(const float4*)&sOut[r][k];
            float4 al = *(const float4*)&sLoop[r][k];
            acc[r] += ai.x * wi[0] + ai.y * wi[1] + ai.z * wi[2] + ai.w * wi[3]
                    + ao.x * wo[0] + ao.y * wo[1] + ao.z * wo[2] + ao.w * wo[3]
                    + al.x * wl[0] + al.y * wl[1] + al.z * wl[2] + al.w * wl[3];
        }
    }
    float b = bias[c];
#pragma unroll
    for (int r = 0; r < TM; ++r) {
        int row = row0 + r;
        if (row < N_ENT)
            out[(size_t)row * DIM + c] = acc[r] * (1.f / 3.f) + b;
    }
}

__global__ __launch_bounds__(256) void bn_stats_kernel(
        const float* __restrict__ pre, float* __restrict__ stats) {
    int c = threadIdx.x;
    if (c >= DIM) return;
    float sum = 0.f, sumsq = 0.f;
    for (int r = blockIdx.x; r < N_ENT; r += gridDim.x) {
        float v = pre[(size_t)r * DIM + c];
        sum += v; sumsq += v * v;
    }
    atomicAdd(&stats[c], sum);
    atomicAdd(&stats[DIM + c], sumsq);
}

__global__ void bn_scale_kernel(
        const float* __restrict__ stats, const float* __restrict__ gamma,
        const float* __restrict__ beta, float* __restrict__ ss) {
    int c = threadIdx.x;
    if (c >= DIM) return;
    float mean = stats[c] * (1.f / (float)N_ENT);
    float var  = stats[DIM + c] * (1.f / (float)N_ENT) - mean * mean;
    float scale = gamma[c] / sqrtf(var + 1e-5f);
    ss[c]       = scale;
    ss[DIM + c] = beta[c] - mean * scale;
}

__global__ __launch_bounds__(256) void bn_tanh_kernel(
        float* __restrict__ out, const float* __restrict__ ss) {
    size_t i = (size_t)blockIdx.x * blockDim.x + threadIdx.x;
    size_t stride = (size_t)gridDim.x * blockDim.x;
    const size_t n4 = (size_t)N_ENT * DIM / 4;
    float4* p = (float4*)out;
    for (; i < n4; i += stride) {
        int c = (int)((i * 4) % DIM);   // DIM % 4 == 0, no row wrap
        float4 v = p[i];
        v.x = tanhf(v.x * ss[c]     + ss[DIM + c]);
        v.y = tanhf(v.y * ss[c + 1] + ss[DIM + c + 1]);
        v.z = tanhf(v.z * ss[c + 2] + ss[DIM + c + 2]);
        v.w = tanhf(v.w * ss[c + 3] + ss[DIM + c + 3]);
        p[i] = v;
    }
}

extern "C" void kernel_launch(void* const* d_in, const int* in_sizes, int n_in,
                              void* d_out, int out_size, void* d_ws, size_t ws_size,
                              hipStream_t stream) {
    const float* ent      = (const float*)d_in[0];
    const float* rel      = (const float*)d_in[1];
    const float* loop_rel = (const float*)d_in[2];
    const float* w_in     = (const float*)d_in[3];
    const float* w_out    = (const float*)d_in[4];
    const float* w_loop   = (const float*)d_in[5];
    const float* bias     = (const float*)d_in[6];
    const float* gamma    = (const float*)d_in[7];
    const float* beta     = (const float*)d_in[8];
    const int*   eidx     = (const int*)d_in[9];
    const int*   etype    = (const int*)d_in[10];
    const int n_edge = in_sizes[10];
    const int* src = eidx;            // edge_index[0]
    const int* dst = eidx + n_edge;   // edge_index[1]

    float* acc_in  = (float*)d_ws;                              // N_ENT*DIM f32
    int*   deg_in  = (int*)(acc_in + (size_t)N_ENT * DIM);      // N_ENT int
    int*   deg_out = deg_in + N_ENT;                            // N_ENT int
    float* stats   = (float*)(deg_out + N_ENT);                 // 2*DIM f32
    float* ss      = stats + 2 * DIM;                           // 2*DIM f32
    float* outp    = (float*)d_out;

    size_t zero_bytes = (size_t)N_ENT * DIM * 4 + (size_t)N_ENT * 8 + 4 * DIM * 4;
    hipMemsetAsync(d_ws, 0, zero_bytes, stream);
    hipMemsetAsync(d_out, 0, (size_t)N_ENT * DIM * 4, stream);

    deg_kernel<<<2048, 256, 0, stream>>>(src, dst, deg_in, deg_out, n_edge);
    scatter_kernel<<<8192, 256, 0, stream>>>(ent, rel, src, dst, etype,
                                             deg_in, deg_out, acc_in, outp, n_edge);
    matmul_kernel<<<(N_ENT + TM - 1) / TM, 256, 0, stream>>>(
        acc_in, outp, ent, loop_rel, w_in, w_out, w_loop, bias, outp);
    bn_stats_kernel<<<512, 256, 0, stream>>>(outp, stats);
    bn_scale_kernel<<<1, 256, 0, stream>>>(stats, gamma, beta, ss);
    bn_tanh_kernel<<<2048, 256, 0, stream>>>(outp, ss);
}

// Round 2
// 1544.429 us; speedup vs baseline: 1.7043x; 1.7043x over previous
//
#include <hip/hip_runtime.h>
#include <math.h>
#include <stdint.h>

#define N_ENT   100000
#define DIM     200
#define HD      100       // DIM/2
#define N_RELC  200
#define TM      32        // rows per block in fused matmul

__device__ __forceinline__ float invsqrt_pos(float x) {
    return x > 0.f ? (1.f / sqrtf(x)) : 0.f;
}

__global__ __launch_bounds__(256) void deg_kernel(
        const int* __restrict__ src, const int* __restrict__ dst,
        int* __restrict__ deg_in, int* __restrict__ deg_out, int n) {
    int i = blockIdx.x * blockDim.x + threadIdx.x;
    int stride = gridDim.x * blockDim.x;
    for (; i < n; i += stride) {
        atomicAdd(&deg_in[dst[i]], 1);
        atomicAdd(&deg_out[src[i]], 1);
    }
}

// Exclusive scan of deg -> off (N_ENT+1 entries) and cursor copy.
// blockIdx 0 -> in arrays, blockIdx 1 -> out arrays. 1024 threads.
__global__ __launch_bounds__(1024) void scan_kernel(
        const int* __restrict__ deg_in, const int* __restrict__ deg_out,
        int* off_in, int* off_out, int* cur_in, int* cur_out) {
    __shared__ int sums[1024];
    const int* deg = blockIdx.x ? deg_out : deg_in;
    int* off = blockIdx.x ? off_out : off_in;
    int* cur = blockIdx.x ? cur_out : cur_in;
    const int t = threadIdx.x;
    const int per = (N_ENT + 1023) / 1024;   // 98
    int lo = t * per, hi = min(lo + per, N_ENT);
    int s = 0;
    for (int i = lo; i < hi; ++i) s += deg[i];
    sums[t] = s;
    __syncthreads();
    // Hillis-Steele inclusive scan
    for (int d = 1; d < 1024; d <<= 1) {
        int v = (t >= d) ? sums[t - d] : 0;
        __syncthreads();
        sums[t] += v;
        __syncthreads();
    }
    int base = (t == 0) ? 0 : sums[t - 1];
    for (int i = lo; i < hi; ++i) {
        off[i] = base; cur[i] = base;
        base += deg[i];
    }
    if (t == 1023) off[N_ENT] = sums[1023];  // thread 1023's chunk is past N_ENT
}

__global__ __launch_bounds__(256) void invdeg_kernel(
        const int* __restrict__ deg_in, const int* __restrict__ deg_out,
        float* __restrict__ inv_in, float* __restrict__ inv_out) {
    int i = blockIdx.x * blockDim.x + threadIdx.x;
    int stride = gridDim.x * blockDim.x;
    for (; i < N_ENT; i += stride) {
        inv_in[i]  = invsqrt_pos((float)deg_in[i]);
        inv_out[i] = invsqrt_pos((float)deg_out[i]);
    }
}

// CSR fill: csr_in indexed by dst holds (src<<8)|etype; csr_out indexed by src
// holds (dst<<8)|etype.  etype < 200 fits in 8 bits; node id < 2^24.
__global__ __launch_bounds__(256) void fill_kernel(
        const int* __restrict__ src, const int* __restrict__ dst,
        const int* __restrict__ etype,
        int* cur_in, int* cur_out,
        uint32_t* __restrict__ csr_in, uint32_t* __restrict__ csr_out, int n) {
    int i = blockIdx.x * blockDim.x + threadIdx.x;
    int stride = gridDim.x * blockDim.x;
    for (; i < n; i += stride) {
        int s = src[i], d = dst[i], t = etype[i];
        int p0 = atomicAdd(&cur_in[d], 1);
        csr_in[p0] = ((uint32_t)s << 8) | (uint32_t)t;
        int p1 = atomicAdd(&cur_out[s], 1);
        csr_out[p1] = ((uint32_t)d << 8) | (uint32_t)t;
    }
}

// One wave per (node, direction). Lanes 0..49 each own a float2 of the
// 100 re elements + the matching float2 of im elements. Register
// accumulate, single plain store. No f32 atomics anywhere.
__global__ __launch_bounds__(256) void gather_kernel(
        const float* __restrict__ ent, const float* __restrict__ rel,
        const uint32_t* __restrict__ csr_in, const uint32_t* __restrict__ csr_out,
        const int* __restrict__ off_in, const int* __restrict__ off_out,
        const float* __restrict__ inv_in, const float* __restrict__ inv_out,
        float* __restrict__ acc_in, float* __restrict__ acc_out) {
    int gwave = (blockIdx.x * blockDim.x + threadIdx.x) >> 6;
    int lane  = threadIdx.x & 63;
    int node  = gwave >> 1;
    int dir   = gwave & 1;
    if (node >= N_ENT) return;
    const uint32_t* csr = dir ? csr_out : csr_in;
    const int*      off = dir ? off_out : off_in;
    const float*    inv = dir ? inv_out : inv_in;
    float*          acc = dir ? acc_out : acc_in;
    const int tofs = dir ? N_RELC : 0;

    int start = off[node], end = off[node + 1];
    const bool active = lane < HD / 2;     // 50 lanes
    const int  p = lane * 2;
    float myinv = inv[node];
    float2 are = {0.f, 0.f}, aim = {0.f, 0.f};

    for (int i = start; i < end; ++i) {
        uint32_t pk = csr[i];
        int s = (int)(pk >> 8);
        int t = (int)(pk & 255u) + tofs;
        float nrm = myinv * inv[s];
        if (active) {
            const float* h = ent + (size_t)s * DIM;
            const float* r = rel + (size_t)t * DIM;
            float2 hre = *(const float2*)(h + p);
            float2 him = *(const float2*)(h + p + HD);
            float2 rre = *(const float2*)(r + p);
            float2 rim = *(const float2*)(r + p + HD);
            are.x += (hre.x * rre.x - him.x * rim.x) * nrm;
            are.y += (hre.y * rre.y - him.y * rim.y) * nrm;
            aim.x += (hre.x * rim.x + him.x * rre.x) * nrm;
            aim.y += (hre.y * rim.y + him.y * rre.y) * nrm;
        }
    }
    if (active) {
        float* o = acc + (size_t)node * DIM;
        *(float2*)(o + p)      = are;
        *(float2*)(o + p + HD) = aim;
    }
}

// Fused: pre = (acc_in@w_in + acc_out@w_out + rotate(ent,loop)@w_loop)/3 + bias
// acc_out lives in d_out; rows staged to LDS then overwritten.
// 512 threads: rowgrp = tid>>8 handles 16 of the 32 rows, c = tid&255 column.
__global__ __launch_bounds__(512) void matmul_kernel(
        const float* __restrict__ acc_in, const float* acc_out,
        const float* __restrict__ ent, const float* __restrict__ loop_rel,
        const float* __restrict__ w_in, const float* __restrict__ w_out,
        const float* __restrict__ w_loop, const float* __restrict__ bias,
        float* out) {
    __shared__ float sIn[TM][DIM];
    __shared__ float sOut[TM][DIM];
    __shared__ float sLoop[TM][DIM];
    const int row0 = blockIdx.x * TM;
    const int tid  = threadIdx.x;

    for (int idx = tid; idx < TM * HD; idx += 512) {
        int r = idx / HD, p = idx % HD;
        int row = row0 + r;
        if (row < N_ENT) {
            size_t base = (size_t)row * DIM;
            sIn[r][p]       = acc_in[base + p];
            sIn[r][p + HD]  = acc_in[base + p + HD];
            sOut[r][p]      = acc_out[base + p];
            sOut[r][p + HD] = acc_out[base + p + HD];
            float e0 = ent[base + p], e1 = ent[base + p + HD];
            float l0 = loop_rel[p],   l1 = loop_rel[p + HD];
            sLoop[r][p]      = e0 * l0 - e1 * l1;
            sLoop[r][p + HD] = e0 * l1 + e1 * l0;
        }
    }
    __syncthreads();

    const int rowgrp = tid >> 8;         // 0 or 1 -> rows [rowgrp*16, +16)
    const int c = tid & 255;
    if (c >= DIM) return;
    float acc[16];
#pragma unroll
    for (int r = 0; r < 16; ++r) acc[r] = 0.f;

    for (int k = 0; k < DIM; k += 4) {
        float wi[4], wo[4], wl[4];
#pragma unroll
        for (int u = 0; u < 4; ++u) {
            wi[u] = w_in [(k + u) * DIM + c];
            wo[u] = w_out[(k + u) * DIM + c];
            wl[u] = w_loop[(k + u) * DIM + c];
        }
#pragma unroll
        for (int r = 0; r < 16; ++r) {
            int row = rowgrp * 16 + r;
            float4 ai = *(const float4*)&sIn[row][k];
            float4 ao = *(const float4*)&sOut[row][k];
            float4 al = *(const float4*)&sLoop[row][k];
            acc[r] += ai.x * wi[0] + ai.y * wi[1] + ai.z * wi[2] + ai.w * wi[3]
                    + ao.x * wo[0] + ao.y * wo[1] + ao.z * wo[2] + ao.w * wo[3]
                    + al.x * wl[0] + al.y * wl[1] + al.z * wl[2] + al.w * wl[3];
        }
    }
    float b = bias[c];
#pragma unroll
    for (int r = 0; r < 16; ++r) {
        int row = row0 + rowgrp * 16 + r;
        if (row < N_ENT)
            out[(size_t)row * DIM + c] = acc[r] * (1.f / 3.f) + b;
    }
}

__global__ __launch_bounds__(256) void bn_stats_kernel(
        const float* __restrict__ pre, float* __restrict__ stats) {
    int c = threadIdx.x;
    if (c >= DIM) return;
    float sum = 0.f, sumsq = 0.f;
    for (int r = blockIdx.x; r < N_ENT; r += gridDim.x) {
        float v = pre[(size_t)r * DIM + c];
        sum += v; sumsq += v * v;
    }
    atomicAdd(&stats[c], sum);
    atomicAdd(&stats[DIM + c], sumsq);
}

__global__ void bn_scale_kernel(
        const float* __restrict__ stats, const float* __restrict__ gamma,
        const float* __restrict__ beta, float* __restrict__ ss) {
    int c = threadIdx.x;
    if (c >= DIM) return;
    float mean = stats[c] * (1.f / (float)N_ENT);
    float var  = stats[DIM + c] * (1.f / (float)N_ENT) - mean * mean;
    float scale = gamma[c] / sqrtf(var + 1e-5f);
    ss[c]       = scale;
    ss[DIM + c] = beta[c] - mean * scale;
}

__global__ __launch_bounds__(256) void bn_tanh_kernel(
        float* __restrict__ out, const float* __restrict__ ss) {
    size_t i = (size_t)blockIdx.x * blockDim.x + threadIdx.x;
    size_t stride = (size_t)gridDim.x * blockDim.x;
    const size_t n4 = (size_t)N_ENT * DIM / 4;
    float4* p = (float4*)out;
    for (; i < n4; i += stride) {
        int c = (int)((i * 4) % DIM);   // DIM % 4 == 0, no row wrap
        float4 v = p[i];
        v.x = tanhf(v.x * ss[c]     + ss[DIM + c]);
        v.y = tanhf(v.y * ss[c + 1] + ss[DIM + c + 1]);
        v.z = tanhf(v.z * ss[c + 2] + ss[DIM + c + 2]);
        v.w = tanhf(v.w * ss[c + 3] + ss[DIM + c + 3]);
        p[i] = v;
    }
}

extern "C" void kernel_launch(void* const* d_in, const int* in_sizes, int n_in,
                              void* d_out, int out_size, void* d_ws, size_t ws_size,
                              hipStream_t stream) {
    const float* ent      = (const float*)d_in[0];
    const float* rel      = (const float*)d_in[1];
    const float* loop_rel = (const float*)d_in[2];
    const float* w_in     = (const float*)d_in[3];
    const float* w_out    = (const float*)d_in[4];
    const float* w_loop   = (const float*)d_in[5];
    const float* bias     = (const float*)d_in[6];
    const float* gamma    = (const float*)d_in[7];
    const float* beta     = (const float*)d_in[8];
    const int*   eidx     = (const int*)d_in[9];
    const int*   etype    = (const int*)d_in[10];
    const int n_edge = in_sizes[10];
    const int* src = eidx;            // edge_index[0]
    const int* dst = eidx + n_edge;   // edge_index[1]

    // workspace layout
    float*    acc_in  = (float*)d_ws;                               // 20e6 f32
    int*      deg_in  = (int*)(acc_in + (size_t)N_ENT * DIM);       // N_ENT
    int*      deg_out = deg_in + N_ENT;                             // N_ENT
    int*      off_in  = deg_out + N_ENT;                            // N_ENT+1
    int*      off_out = off_in + N_ENT + 1;                         // N_ENT+1
    int*      cur_in  = off_out + N_ENT + 1;                        // N_ENT
    int*      cur_out = cur_in + N_ENT;                             // N_ENT
    float*    inv_in  = (float*)(cur_out + N_ENT);                  // N_ENT
    float*    inv_out = inv_in + N_ENT;                             // N_ENT
    uint32_t* csr_in  = (uint32_t*)(inv_out + N_ENT);               // n_edge
    uint32_t* csr_out = csr_in + n_edge;                            // n_edge
    float*    stats   = (float*)(csr_out + n_edge);                 // 2*DIM
    float*    ss      = stats + 2 * DIM;                            // 2*DIM
    float*    outp    = (float*)d_out;

    // zero: degrees + stats
    hipMemsetAsync(deg_in, 0, (size_t)2 * N_ENT * sizeof(int), stream);
    hipMemsetAsync(stats, 0, (size_t)2 * DIM * sizeof(float), stream);

    deg_kernel<<<2048, 256, 0, stream>>>(src, dst, deg_in, deg_out, n_edge);
    scan_kernel<<<2, 1024, 0, stream>>>(deg_in, deg_out, off_in, off_out,
                                        cur_in, cur_out);
    invdeg_kernel<<<512, 256, 0, stream>>>(deg_in, deg_out, inv_in, inv_out);
    fill_kernel<<<2048, 256, 0, stream>>>(src, dst, etype, cur_in, cur_out,
                                          csr_in, csr_out, n_edge);
    // 200000 waves = 2 per node (in/out); 4 waves per block
    gather_kernel<<<50000, 256, 0, stream>>>(ent, rel, csr_in, csr_out,
                                             off_in, off_out, inv_in, inv_out,
                                             acc_in, outp);
    matmul_kernel<<<(N_ENT + TM - 1) / TM, 512, 0, stream>>>(
        acc_in, outp, ent, loop_rel, w_in, w_out, w_loop, bias, outp);
    bn_stats_kernel<<<512, 256, 0, stream>>>(outp, stats);
    bn_scale_kernel<<<1, 256, 0, stream>>>(stats, gamma, beta, ss);
    bn_tanh_kernel<<<2048, 256, 0, stream>>>(outp, ss);
}

// Round 3
// 993.916 us; speedup vs baseline: 2.6483x; 1.5539x over previous
//
#include <hip/hip_runtime.h>
#include <math.h>
#include <stdint.h>

#define N_ENT   100000
#define DIM     200
#define HD      100       // DIM/2
#define N_RELC  200
#define KP      608       // padded K: 3*200 -> 19*32
#define BM      128
#define BNN     256       // padded N (200 -> 256)
#define NT      19        // K steps of 32
#define MPAD    100096    // 782 * 128

typedef uint32_t u32;
typedef __attribute__((ext_vector_type(8))) short bf16x8;
typedef __attribute__((ext_vector_type(4))) float f32x4;

__device__ __forceinline__ float invsqrt_pos(float x) {
    return x > 0.f ? (1.f / sqrtf(x)) : 0.f;
}

__device__ __forceinline__ u32 pack_bf16x2(float a, float b) {
    u32 ua = __float_as_uint(a), ub = __float_as_uint(b);
    ua = (ua + 0x7FFFu + ((ua >> 16) & 1u)) >> 16;
    ub = (ub + 0x7FFFu + ((ub >> 16) & 1u)) >> 16;
    return ua | (ub << 16);
}

// global -> LDS direct copy, 16B per lane (dest must be linear in lane id)
__device__ __forceinline__ void lds_cp16(void* lds, const void* g) {
    auto gp = (const __attribute__((address_space(1))) u32*)(uintptr_t)g;
    auto lp = (__attribute__((address_space(3))) u32*)(u32)(uintptr_t)lds;
    __builtin_amdgcn_global_load_lds(gp, lp, 16, 0, 0);
}

__global__ __launch_bounds__(256) void deg_kernel(
        const int* __restrict__ src, const int* __restrict__ dst,
        int* __restrict__ deg_in, int* __restrict__ deg_out, int n) {
    int i = blockIdx.x * blockDim.x + threadIdx.x;
    int stride = gridDim.x * blockDim.x;
    for (; i < n; i += stride) {
        atomicAdd(&deg_in[dst[i]], 1);
        atomicAdd(&deg_out[src[i]], 1);
    }
}

// Exclusive scan of deg -> off (N_ENT+1) and cursor copy. block 0: in, 1: out.
__global__ __launch_bounds__(1024) void scan_kernel(
        const int* __restrict__ deg_in, const int* __restrict__ deg_out,
        int* off_in, int* off_out, int* cur_in, int* cur_out) {
    __shared__ int sums[1024];
    const int* deg = blockIdx.x ? deg_out : deg_in;
    int* off = blockIdx.x ? off_out : off_in;
    int* cur = blockIdx.x ? cur_out : cur_in;
    const int t = threadIdx.x;
    const int per = (N_ENT + 1023) / 1024;   // 98
    int lo = t * per, hi = min(lo + per, N_ENT);
    int s = 0;
    for (int i = lo; i < hi; ++i) s += deg[i];
    sums[t] = s;
    __syncthreads();
    for (int d = 1; d < 1024; d <<= 1) {
        int v = (t >= d) ? sums[t - d] : 0;
        __syncthreads();
        sums[t] += v;
        __syncthreads();
    }
    int base = (t == 0) ? 0 : sums[t - 1];
    for (int i = lo; i < hi; ++i) {
        off[i] = base; cur[i] = base;
        base += deg[i];
    }
    if (t == 1023) off[N_ENT] = sums[1023];
}

__global__ __launch_bounds__(256) void invdeg_kernel(
        const int* __restrict__ deg_in, const int* __restrict__ deg_out,
        float* __restrict__ inv_in, float* __restrict__ inv_out) {
    int i = blockIdx.x * blockDim.x + threadIdx.x;
    int stride = gridDim.x * blockDim.x;
    for (; i < N_ENT; i += stride) {
        inv_in[i]  = invsqrt_pos((float)deg_in[i]);
        inv_out[i] = invsqrt_pos((float)deg_out[i]);
    }
}

// csr_in indexed by dst holds (src<<8)|etype; csr_out by src holds (dst<<8)|etype
__global__ __launch_bounds__(256) void fill_kernel(
        const int* __restrict__ src, const int* __restrict__ dst,
        const int* __restrict__ etype,
        int* cur_in, int* cur_out,
        u32* __restrict__ csr_in, u32* __restrict__ csr_out, int n) {
    int i = blockIdx.x * blockDim.x + threadIdx.x;
    int stride = gridDim.x * blockDim.x;
    for (; i < n; i += stride) {
        int s = src[i], d = dst[i], t = etype[i];
        int p0 = atomicAdd(&cur_in[d], 1);
        csr_in[p0] = ((u32)s << 8) | (u32)t;
        int p1 = atomicAdd(&cur_out[s], 1);
        csr_out[p1] = ((u32)d << 8) | (u32)t;
    }
}

// B^T [256][KP] bf16: row c = output column c; k rows 600+ and cols 200+ zero.
__global__ __launch_bounds__(256) void prep_bt_kernel(
        const float* __restrict__ w_in, const float* __restrict__ w_out,
        const float* __restrict__ w_loop, ushort* __restrict__ BT) {
    int i = blockIdx.x * 256 + threadIdx.x;
    if (i >= 256 * KP) return;
    int c = i / KP, k = i % KP;
    float v = 0.f;
    if (c < DIM) {
        if (k < 200)      v = w_in[k * DIM + c];
        else if (k < 400) v = w_out[(k - 200) * DIM + c];
        else if (k < 600) v = w_loop[(k - 400) * DIM + c];
    }
    u32 u = __float_as_uint(v);
    u = (u + 0x7FFFu + ((u >> 16) & 1u)) >> 16;
    BT[i] = (ushort)u;
}

// One wave per node: in-dir gather, out-dir gather, loop rotation.
// Writes bf16 row of A: [in(200) | out(200) | loop(200) | zeros(8)]
__global__ __launch_bounds__(256) void gather_kernel(
        const float* __restrict__ ent, const float* __restrict__ rel,
        const float* __restrict__ loop_rel,
        const u32* __restrict__ csr_in, const u32* __restrict__ csr_out,
        const int* __restrict__ off_in, const int* __restrict__ off_out,
        const float* __restrict__ inv_in, const float* __restrict__ inv_out,
        ushort* __restrict__ Abuf) {
    int node = (blockIdx.x * blockDim.x + threadIdx.x) >> 6;
    int lane = threadIdx.x & 63;
    if (node >= N_ENT) return;
    const bool act = lane < 50;
    const int p = lane * 2;
    u32* Arow = (u32*)(Abuf + (size_t)node * KP);

    if (lane >= 50 && lane < 54) Arow[300 + (lane - 50)] = 0u;  // cols 600..607

#pragma unroll
    for (int dir = 0; dir < 2; ++dir) {
        const u32* csr = dir ? csr_out : csr_in;
        const int* off = dir ? off_out : off_in;
        const float* inv = dir ? inv_out : inv_in;
        const int tofs = dir ? N_RELC : 0;
        float myinv = inv[node];
        float2 are = {0.f, 0.f}, aim = {0.f, 0.f};
        int i0 = off[node], i1 = off[node + 1];
        for (int i = i0; i < i1; ++i) {
            u32 pk = csr[i];
            int s = (int)(pk >> 8);
            int t = (int)(pk & 255u) + tofs;
            float nrm = myinv * inv[s];
            if (act) {
                const float* h = ent + (size_t)s * DIM;
                const float* r = rel + (size_t)t * DIM;
                float2 hre = *(const float2*)(h + p);
                float2 him = *(const float2*)(h + p + HD);
                float2 rre = *(const float2*)(r + p);
                float2 rim = *(const float2*)(r + p + HD);
                are.x += (hre.x * rre.x - him.x * rim.x) * nrm;
                are.y += (hre.y * rre.y - him.y * rim.y) * nrm;
                aim.x += (hre.x * rim.x + him.x * rre.x) * nrm;
                aim.y += (hre.y * rim.y + him.y * rre.y) * nrm;
            }
        }
        if (act) {
            Arow[dir * 100 + lane]      = pack_bf16x2(are.x, are.y);
            Arow[dir * 100 + 50 + lane] = pack_bf16x2(aim.x, aim.y);
        }
    }
    if (act) {
        const float* h = ent + (size_t)node * DIM;
        float2 hre = *(const float2*)(h + p);
        float2 him = *(const float2*)(h + p + HD);
        float2 lre = *(const float2*)(loop_rel + p);
        float2 lim = *(const float2*)(loop_rel + p + HD);
        float rx = hre.x * lre.x - him.x * lim.x;
        float ry = hre.y * lre.y - him.y * lim.y;
        float ix = hre.x * lim.x + him.x * lre.x;
        float iy = hre.y * lim.y + him.y * lre.y;
        Arow[200 + lane] = pack_bf16x2(rx, ry);
        Arow[250 + lane] = pack_bf16x2(ix, iy);
    }
}

// C = A(MPADxKP) @ BT^T -> pre (f32), *1/3 + bias. MFMA bf16 16x16x32.
// 8 waves 2Mx4N, wave tile 64x64, double-buffered LDS via global_load_lds.
__global__ __launch_bounds__(512, 4) void gemm_kernel(
        const ushort* __restrict__ A, const ushort* __restrict__ BT,
        const float* __restrict__ bias, float* __restrict__ out) {
    __shared__ ushort Asm[2][BM * 32];
    __shared__ ushort Bsm[2][BNN * 32];
    const int tid = threadIdx.x;
    const int row0 = blockIdx.x * BM;
    const int l = tid & 63;
    const int w = tid >> 6;
    const int wm = w >> 2;          // 0..1
    const int wn = w & 3;           // 0..3

    f32x4 acc[4][4];
#pragma unroll
    for (int i = 0; i < 4; ++i)
#pragma unroll
        for (int j = 0; j < 4; ++j)
            acc[i][j] = (f32x4){0.f, 0.f, 0.f, 0.f};

    {   // stage K-step 0 into buf 0
        int r = tid >> 2, s = tid & 3;
        lds_cp16(&Asm[0][tid * 8], A + (size_t)(row0 + r) * KP + s * 8);
#pragma unroll
        for (int j = 0; j < 2; ++j) {
            int c = tid + j * 512;
            int br = c >> 2, bs = c & 3;
            lds_cp16(&Bsm[0][c * 8], BT + (size_t)br * KP + bs * 8);
        }
    }

    int cur = 0;
    for (int ks = 0; ks < NT; ++ks) {
        __syncthreads();           // compiler drains vmcnt+lgkmcnt here
        if (ks + 1 < NT) {
            const int k0 = (ks + 1) * 32;
            int r = tid >> 2, s = tid & 3;
            lds_cp16(&Asm[cur ^ 1][tid * 8], A + (size_t)(row0 + r) * KP + k0 + s * 8);
#pragma unroll
            for (int j = 0; j < 2; ++j) {
                int c = tid + j * 512;
                int br = c >> 2, bs = c & 3;
                lds_cp16(&Bsm[cur ^ 1][c * 8], BT + (size_t)br * KP + k0 + bs * 8);
            }
        }
        const int kq = (l >> 4) * 8;
        const int lr = l & 15;
        bf16x8 aF[4], bF[4];
#pragma unroll
        for (int mf = 0; mf < 4; ++mf)
            aF[mf] = *(const bf16x8*)&Asm[cur][(wm * 64 + mf * 16 + lr) * 32 + kq];
#pragma unroll
        for (int nf = 0; nf < 4; ++nf)
            bF[nf] = *(const bf16x8*)&Bsm[cur][(wn * 64 + nf * 16 + lr) * 32 + kq];
#pragma unroll
        for (int mf = 0; mf < 4; ++mf)
#pragma unroll
            for (int nf = 0; nf < 4; ++nf)
                acc[mf][nf] = __builtin_amdgcn_mfma_f32_16x16x32_bf16(
                        aF[mf], bF[nf], acc[mf][nf], 0, 0, 0);
        cur ^= 1;
    }

    const int lr = l & 15;
    const int rq = (l >> 4) * 4;
#pragma unroll
    for (int nf = 0; nf < 4; ++nf) {
        int gcol = wn * 64 + nf * 16 + lr;
        if (gcol >= DIM) continue;
        float b = bias[gcol];
#pragma unroll
        for (int mf = 0; mf < 4; ++mf) {
            int grow0 = row0 + wm * 64 + mf * 16 + rq;
#pragma unroll
            for (int r = 0; r < 4; ++r) {
                int grow = grow0 + r;
                if (grow < N_ENT)
                    out[(size_t)grow * DIM + gcol] = acc[mf][nf][r] * (1.f / 3.f) + b;
            }
        }
    }
}

__global__ __launch_bounds__(256) void bn_stats_kernel(
        const float* __restrict__ pre, float* __restrict__ stats) {
    int c = threadIdx.x;
    if (c >= DIM) return;
    float sum = 0.f, sumsq = 0.f;
    for (int r = blockIdx.x; r < N_ENT; r += gridDim.x) {
        float v = pre[(size_t)r * DIM + c];
        sum += v; sumsq += v * v;
    }
    atomicAdd(&stats[c], sum);
    atomicAdd(&stats[DIM + c], sumsq);
}

__global__ void bn_scale_kernel(
        const float* __restrict__ stats, const float* __restrict__ gamma,
        const float* __restrict__ beta, float* __restrict__ ss) {
    int c = threadIdx.x;
    if (c >= DIM) return;
    float mean = stats[c] * (1.f / (float)N_ENT);
    float var  = stats[DIM + c] * (1.f / (float)N_ENT) - mean * mean;
    float scale = gamma[c] / sqrtf(var + 1e-5f);
    ss[c]       = scale;
    ss[DIM + c] = beta[c] - mean * scale;
}

__global__ __launch_bounds__(256) void bn_tanh_kernel(
        float* __restrict__ out, const float* __restrict__ ss) {
    size_t i = (size_t)blockIdx.x * blockDim.x + threadIdx.x;
    size_t stride = (size_t)gridDim.x * blockDim.x;
    const size_t n4 = (size_t)N_ENT * DIM / 4;
    float4* p = (float4*)out;
    for (; i < n4; i += stride) {
        int c = (int)((i * 4) % DIM);
        float4 v = p[i];
        v.x = tanhf(v.x * ss[c]     + ss[DIM + c]);
        v.y = tanhf(v.y * ss[c + 1] + ss[DIM + c + 1]);
        v.z = tanhf(v.z * ss[c + 2] + ss[DIM + c + 2]);
        v.w = tanhf(v.w * ss[c + 3] + ss[DIM + c + 3]);
        p[i] = v;
    }
}

extern "C" void kernel_launch(void* const* d_in, const int* in_sizes, int n_in,
                              void* d_out, int out_size, void* d_ws, size_t ws_size,
                              hipStream_t stream) {
    const float* ent      = (const float*)d_in[0];
    const float* rel      = (const float*)d_in[1];
    const float* loop_rel = (const float*)d_in[2];
    const float* w_in     = (const float*)d_in[3];
    const float* w_out    = (const float*)d_in[4];
    const float* w_loop   = (const float*)d_in[5];
    const float* bias     = (const float*)d_in[6];
    const float* gamma    = (const float*)d_in[7];
    const float* beta     = (const float*)d_in[8];
    const int*   eidx     = (const int*)d_in[9];
    const int*   etype    = (const int*)d_in[10];
    const int n_edge = in_sizes[10];
    const int* src = eidx;
    const int* dst = eidx + n_edge;

    // workspace layout
    ushort* Abuf   = (ushort*)d_ws;                        // MPAD*KP bf16 (121.7MB)
    ushort* BT     = Abuf + (size_t)MPAD * KP;             // 256*KP bf16
    int* deg_in    = (int*)(BT + 256 * KP);
    int* deg_out   = deg_in + N_ENT;
    int* off_in    = deg_out + N_ENT;
    int* off_out   = off_in + N_ENT + 1;
    int* cur_in    = off_out + N_ENT + 1;
    int* cur_out   = cur_in + N_ENT;
    float* inv_in  = (float*)(cur_out + N_ENT);
    float* inv_out = inv_in + N_ENT;
    u32* csr_in    = (u32*)(inv_out + N_ENT);              // n_edge
    u32* csr_out   = csr_in + n_edge;                      // n_edge
    float* stats   = (float*)(csr_out + n_edge);           // 2*DIM
    float* ss      = stats + 2 * DIM;                      // 2*DIM
    float* outp    = (float*)d_out;

    hipMemsetAsync(deg_in, 0, (size_t)2 * N_ENT * sizeof(int), stream);
    hipMemsetAsync(stats, 0, (size_t)2 * DIM * sizeof(float), stream);

    deg_kernel<<<2048, 256, 0, stream>>>(src, dst, deg_in, deg_out, n_edge);
    scan_kernel<<<2, 1024, 0, stream>>>(deg_in, deg_out, off_in, off_out,
                                        cur_in, cur_out);
    invdeg_kernel<<<512, 256, 0, stream>>>(deg_in, deg_out, inv_in, inv_out);
    fill_kernel<<<2048, 256, 0, stream>>>(src, dst, etype, cur_in, cur_out,
                                          csr_in, csr_out, n_edge);
    prep_bt_kernel<<<(256 * KP + 255) / 256, 256, 0, stream>>>(w_in, w_out, w_loop, BT);
    gather_kernel<<<25000, 256, 0, stream>>>(ent, rel, loop_rel, csr_in, csr_out,
                                             off_in, off_out, inv_in, inv_out, Abuf);
    gemm_kernel<<<MPAD / BM, 512, 0, stream>>>(Abuf, BT, bias, outp);
    bn_stats_kernel<<<512, 256, 0, stream>>>(outp, stats);
    bn_scale_kernel<<<1, 256, 0, stream>>>(stats, gamma, beta, ss);
    bn_tanh_kernel<<<2048, 256, 0, stream>>>(outp, ss);
}